// Round 9
// baseline (107.881 us; speedup 1.0000x reference)
//
#include <hip/hip_runtime.h>

// SNN forward: T=128, B=8192, I=2, H=256, O=2
//  cur[t,b,h] = x[t,b,0]*W1[h,0] + x[t,b,1]*W1[h,1]
//  scan: reset = (mem>1); mem = 0.9*mem + cur - reset; spk = (mem>1)
//  out[b,o] = (mean of spk over last 10 t) dot W2[o,:]
//
// R9 = R8 with PF 8 -> 16: a discriminating probe between the two readings of
// R8's counters (VALUBusy 78%, dur flat vs R5 despite 2x TLP):
//  (a) effective-issue-bound (~42 us of VALU busy ~ m07's 103 TF scalar fp32
//      ceiling): PF=16 changes nothing -> declare VALU roofline.
//  (b) latency-bound with VALUBusy overcounted by the gfx94x 4-cyc fallback
//      formula: 32 loads in flight (~1 us cover/wave) -> dur ~46-50 us.
// Instruction count is locked at 8 fp32 ops/chain-step: per-op _rn rounding
// (no FMA / packed / fp64 / truncation) is required for bit-exact spikes.
//
// Kept from R8: lane=batch, coalesced float2 saddr-form loads, XCD swizzle
// (bg=blockIdx&127, hg=blockIdx>>7 -> all sharers of one x-slice on XCD bg%8),
// RH=4, grid 2048 (8 waves/SIMD), no launch-bounds clamp (R7's forced
// VGPR=32 spilled 17 MB to scratch), two-kernel h-partial reduction.
//
// Spike-path numerics: __fmul_rn/__fadd_rn/__fsub_rn, identical op order to
// the absmax-0.0 kernels (R1/R2/R4/R5/R7/R8).

#define T_STEPS 128
#define BATCH   8192
#define HID     256
#define TAIL    10
#define RH      4      // hidden chains per thread
#define LB      64     // batch rows per block (= lanes per wave)
#define NWAVE   4      // waves per block; block covers NWAVE*RH = 16 h
#define HG      16     // h-groups (HID / 16)
#define NBG     (BATCH / LB)   // 128 batch groups
#define PF      16     // prefetch depth (t-steps in flight)

__global__ __launch_bounds__(256) void snn_scan(const float* __restrict__ x,
                                                const float* __restrict__ W1,
                                                const float* __restrict__ W2,
                                                float2* __restrict__ partial) {
    const int tid   = threadIdx.x;
    const int lane  = tid & 63;
    const int wave  = tid >> 6;
    const int bg    = blockIdx.x & (NBG - 1);  // same bg -> same XCD for all hg
    const int hg    = blockIdx.x >> 7;
    const int b     = bg * LB + lane;          // batch row (lane part of addr)
    const int hbase = hg * (NWAVE * RH) + wave * RH;

    // W1 rows for my 4 h (wave-uniform addresses -> scalarized, one-time)
    float w0[RH], w1[RH];
#pragma unroll
    for (int r = 0; r < RH; ++r) {
        w0[r] = W1[2 * (hbase + r)];
        w1[r] = W1[2 * (hbase + r) + 1];
    }

    // Uniform-base addressing: xp + t*BATCH is wave-uniform (SGPR base,
    // stepped by SALU); + b is the fixed per-lane voffset.
    const float2* xp = (const float2*)x;

    float mem[RH], spk[RH], cnt[RH];
#pragma unroll
    for (int r = 0; r < RH; ++r) { mem[r] = 0.0f; spk[r] = 0.0f; cnt[r] = 0.0f; }

#define LOADX(t) xp[(size_t)(t) * BATCH + b]

#define STEP(r, xa, xc)                                                           \
    {                                                                             \
        const float c = __fadd_rn(__fmul_rn((xa), w0[r]), __fmul_rn((xc), w1[r]));\
        mem[r] = __fsub_rn(__fadd_rn(__fmul_rn(0.9f, mem[r]), c), spk[r]);        \
        spk[r] = (mem[r] > 1.0f) ? 1.0f : 0.0f;                                   \
    }

    // ---- warm-up: fill rotating prefetch buffer with t = 0..15 ----
    float2 buf[PF];
#pragma unroll
    for (int j = 0; j < PF; ++j) buf[j] = LOADX(j);

    // ---- main loop: t = 0..95 (6 iters), prefetch t+16 (<= 111) ----
    for (int tb = 0; tb < T_STEPS - 2 * PF; tb += PF) {
#pragma unroll
        for (int j = 0; j < PF; ++j) {
            const float2 xv = buf[j];
            buf[j] = LOADX(tb + PF + j);
#pragma unroll
            for (int r = 0; r < RH; ++r) STEP(r, xv.x, xv.y)
        }
    }

    // ---- t = 96..111: consume buf[j], refill with t = 112..127 ----
#pragma unroll
    for (int j = 0; j < PF; ++j) {
        const float2 xv = buf[j];
        buf[j] = LOADX(T_STEPS - PF + j);
#pragma unroll
        for (int r = 0; r < RH; ++r) STEP(r, xv.x, xv.y)
    }
    // ---- t = 112..127 (count t >= 118, i.e. j >= 6) ----
#pragma unroll
    for (int j = 0; j < PF; ++j) {
        const float2 xv = buf[j];
#pragma unroll
        for (int r = 0; r < RH; ++r) {
            STEP(r, xv.x, xv.y)
            if (j >= PF - TAIL) cnt[r] += spk[r];   // integer-valued, exact
        }
    }
#undef STEP
#undef LOADX

    // per-thread partial of out[b, :] over my 4 h (ascending h order)
    float p0 = 0.0f, p1 = 0.0f;
#pragma unroll
    for (int r = 0; r < RH; ++r) {
        const float avg = cnt[r] / 10.0f;
        p0 = __fadd_rn(p0, __fmul_rn(avg, W2[hbase + r]));
        p1 = __fadd_rn(p1, __fmul_rn(avg, W2[HID + hbase + r]));
    }

    // combine the block's 4 waves (different h-chunks, same b per lane)
    __shared__ float2 red[NWAVE][LB];
    red[wave][lane] = make_float2(p0, p1);
    __syncthreads();
    if (wave == 0) {
        const float2 a0 = red[0][lane], a1 = red[1][lane];
        const float2 a2 = red[2][lane], a3 = red[3][lane];
        float2 s;
        s.x = __fadd_rn(__fadd_rn(a0.x, a1.x), __fadd_rn(a2.x, a3.x));
        s.y = __fadd_rn(__fadd_rn(a0.y, a1.y), __fadd_rn(a2.y, a3.y));
        partial[(size_t)hg * BATCH + b] = s;
    }
}

// sum the 16 h-group partials -> out[b, 0:2]
__global__ __launch_bounds__(256) void snn_reduce(const float2* __restrict__ partial,
                                                  float2* __restrict__ out) {
    const int b = blockIdx.x * 256 + threadIdx.x;   // 8192 threads
    float sx = 0.0f, sy = 0.0f;
#pragma unroll
    for (int hg = 0; hg < HG; ++hg) {
        const float2 p = partial[(size_t)hg * BATCH + b];
        sx = __fadd_rn(sx, p.x);
        sy = __fadd_rn(sy, p.y);
    }
    out[b] = make_float2(sx, sy);
}

extern "C" void kernel_launch(void* const* d_in, const int* in_sizes, int n_in,
                              void* d_out, int out_size, void* d_ws, size_t ws_size,
                              hipStream_t stream) {
    const float* x  = (const float*)d_in[0];  // (128, 8192, 2)
    const float* W1 = (const float*)d_in[1];  // (256, 2)
    const float* W2 = (const float*)d_in[2];  // (2, 256)
    float2* out     = (float2*)d_out;         // (8192, 2)
    float2* partial = (float2*)d_ws;          // (16, 8192) float2 = 1 MB scratch

    snn_scan<<<NBG * HG, 256, 0, stream>>>(x, W1, W2, partial);
    snn_reduce<<<BATCH / 256, 256, 0, stream>>>(partial, out);
}

// Round 10
// 102.725 us; speedup vs baseline: 1.0502x; 1.0502x over previous
//
#include <hip/hip_runtime.h>

// SNN forward: T=128, B=8192, I=2, H=256, O=2
//  cur[t,b,h] = x[t,b,0]*W1[h,0] + x[t,b,1]*W1[h,1]
//  scan: reset = (mem>1); mem = 0.9*mem + cur - reset; spk = (mem>1)
//  out[b,o] = (mean of spk over last 10 t) dot W2[o,:]
//
// R10 = best-of-ladder combination:
//  - RH=8 chains/thread (R5): 64 chain-ops per t per thread amortizes the
//    load + loop overhead 2x better than RH=4; R5's busy time (39 us) was
//    the lowest measured. Grid 1024 (HG=8).
//  - saddr-form addressing (R8): loads written as xp[t*BATCH + b] with the
//    t-offset wave-uniform -> SGPR base stepped by SALU, fixed VGPR voffset,
//    ZERO per-load VALU (R5 paid v_add_co/v_addc per load).
//  - PF=8 rotating register prefetch (R9 showed PF=16 only adds pressure:
//    the kernel is VALU-issue-bound, not latency-bound).
//  - no launch-bounds clamp (R7's forced VGPR=32 spilled 17 MB).
// Issue-rate context: sustained scalar fp32 issue on gfx950 measures
// ~3.05 cyc/wave-instr (m07: 103 TF), so the locked 8-op/chain-step stream
// floors at ~42 us busy; this round squeezes overhead/idle around it.
// XCD swizzle: bg=blockIdx&127, hg=blockIdx>>7 -> all 8 hg-sharers of one
// x-slice land on XCD bg%8 -> one L2 fill serves all.
//
// Spike-path numerics: per-op fp32 rounding (__fmul_rn/__fadd_rn/__fsub_rn,
// no FMA), identical op order + epilogue reduction order to the absmax-0.0
// kernels (R1/R2/R4/R5/R7/R8/R9).

#define T_STEPS 128
#define BATCH   8192
#define HID     256
#define TAIL    10
#define RH      8      // hidden chains per thread
#define LB      64     // batch rows per block (= lanes per wave)
#define NWAVE   4      // waves per block; block covers NWAVE*RH = 32 h
#define HG      8      // h-groups (HID / 32)
#define NBG     (BATCH / LB)   // 128 batch groups
#define PF      8      // prefetch depth (t-steps in flight)

__global__ __launch_bounds__(256) void snn_scan(const float* __restrict__ x,
                                                const float* __restrict__ W1,
                                                const float* __restrict__ W2,
                                                float2* __restrict__ partial) {
    const int tid   = threadIdx.x;
    const int lane  = tid & 63;
    const int wave  = tid >> 6;
    const int bg    = blockIdx.x & (NBG - 1);  // same bg -> same XCD for all hg
    const int hg    = blockIdx.x >> 7;
    const int b     = bg * LB + lane;          // batch row (lane part of addr)
    const int hbase = hg * (NWAVE * RH) + wave * RH;

    // W1 rows for my 8 h (wave-uniform addresses -> scalarized, one-time)
    float w0[RH], w1[RH];
#pragma unroll
    for (int r = 0; r < RH; ++r) {
        w0[r] = W1[2 * (hbase + r)];
        w1[r] = W1[2 * (hbase + r) + 1];
    }

    // Uniform-base addressing: xp + t*BATCH is wave-uniform (SGPR base,
    // SALU-stepped); + b is the fixed per-lane voffset.
    const float2* xp = (const float2*)x;

    float mem[RH], spk[RH], cnt[RH];
#pragma unroll
    for (int r = 0; r < RH; ++r) { mem[r] = 0.0f; spk[r] = 0.0f; cnt[r] = 0.0f; }

#define LOADX(t) xp[(size_t)(t) * BATCH + b]

#define STEP(r, xa, xc)                                                           \
    {                                                                             \
        const float c = __fadd_rn(__fmul_rn((xa), w0[r]), __fmul_rn((xc), w1[r]));\
        mem[r] = __fsub_rn(__fadd_rn(__fmul_rn(0.9f, mem[r]), c), spk[r]);        \
        spk[r] = (mem[r] > 1.0f) ? 1.0f : 0.0f;                                   \
    }

    // ---- warm-up: fill rotating prefetch buffer with t = 0..7 ----
    float2 buf[PF];
#pragma unroll
    for (int j = 0; j < PF; ++j) buf[j] = LOADX(j);

    // ---- main loop: t = 0..111 (14 iters), prefetch t+8 (<= 119) ----
    for (int tb = 0; tb < T_STEPS - 2 * PF; tb += PF) {
#pragma unroll
        for (int j = 0; j < PF; ++j) {
            const float2 xv = buf[j];
            buf[j] = LOADX(tb + PF + j);
#pragma unroll
            for (int r = 0; r < RH; ++r) STEP(r, xv.x, xv.y)
        }
    }

    // ---- t = 112..119: consume buf[j], refill with t = 120..127 ----
#pragma unroll
    for (int j = 0; j < PF; ++j) {
        const float2 xv = buf[j];
        buf[j] = LOADX(T_STEPS - PF + j);
#pragma unroll
        for (int r = 0; r < RH; ++r) {
            STEP(r, xv.x, xv.y)
            if (j >= PF - 2) cnt[r] += spk[r];   // t = 118, 119
        }
    }
    // ---- t = 120..127 (all counted) ----
#pragma unroll
    for (int j = 0; j < PF; ++j) {
        const float2 xv = buf[j];
#pragma unroll
        for (int r = 0; r < RH; ++r) {
            STEP(r, xv.x, xv.y)
            cnt[r] += spk[r];   // integer-valued, exact in fp32
        }
    }
#undef STEP
#undef LOADX

    // per-thread partial of out[b, :] over my 8 h (ascending h order)
    float p0 = 0.0f, p1 = 0.0f;
#pragma unroll
    for (int r = 0; r < RH; ++r) {
        const float avg = cnt[r] / 10.0f;
        p0 = __fadd_rn(p0, __fmul_rn(avg, W2[hbase + r]));
        p1 = __fadd_rn(p1, __fmul_rn(avg, W2[HID + hbase + r]));
    }

    // combine the block's 4 waves (different h-chunks, same b per lane)
    __shared__ float2 red[NWAVE][LB];
    red[wave][lane] = make_float2(p0, p1);
    __syncthreads();
    if (wave == 0) {
        const float2 a0 = red[0][lane], a1 = red[1][lane];
        const float2 a2 = red[2][lane], a3 = red[3][lane];
        float2 s;
        s.x = __fadd_rn(__fadd_rn(a0.x, a1.x), __fadd_rn(a2.x, a3.x));
        s.y = __fadd_rn(__fadd_rn(a0.y, a1.y), __fadd_rn(a2.y, a3.y));
        partial[(size_t)hg * BATCH + b] = s;
    }
}

// sum the 8 h-group partials -> out[b, 0:2]
__global__ __launch_bounds__(256) void snn_reduce(const float2* __restrict__ partial,
                                                  float2* __restrict__ out) {
    const int b = blockIdx.x * 256 + threadIdx.x;   // 8192 threads
    float sx = 0.0f, sy = 0.0f;
#pragma unroll
    for (int hg = 0; hg < HG; ++hg) {
        const float2 p = partial[(size_t)hg * BATCH + b];
        sx = __fadd_rn(sx, p.x);
        sy = __fadd_rn(sy, p.y);
    }
    out[b] = make_float2(sx, sy);
}

extern "C" void kernel_launch(void* const* d_in, const int* in_sizes, int n_in,
                              void* d_out, int out_size, void* d_ws, size_t ws_size,
                              hipStream_t stream) {
    const float* x  = (const float*)d_in[0];  // (128, 8192, 2)
    const float* W1 = (const float*)d_in[1];  // (256, 2)
    const float* W2 = (const float*)d_in[2];  // (2, 256)
    float2* out     = (float2*)d_out;         // (8192, 2)
    float2* partial = (float2*)d_ws;          // (8, 8192) float2 = 512 KB scratch

    snn_scan<<<NBG * HG, 256, 0, stream>>>(x, W1, W2, partial);
    snn_reduce<<<BATCH / 256, 256, 0, stream>>>(partial, out);
}